// Round 14
// baseline (175.341 us; speedup 1.0000x reference)
//
#include <hip/hip_runtime.h>

// ---------------------------------------------------------------------------
// Mutual Feature Refinement — round 14.
// Delta from round 13 (passing, 168.3 µs): proj128_k and wgemm_epi_k staging
// switched from reg-staging to global_load_lds (m97 ladder step): linear LDS
// dest chunks, per-lane gathered global source mapped onto the SAME padded
// 80-stride layout (pad pieces load col 0, never read). Fragment reads and
// all numerics byte-identical. LDS/block 40KB -> 4 blocks/CU.
// flash_k / bn2_k / wcvt8_k byte-identical to round 13.
// ---------------------------------------------------------------------------

typedef __bf16 bf16x8 __attribute__((ext_vector_type(8)));
typedef float  f32x4  __attribute__((ext_vector_type(4)));
typedef float  f32x16 __attribute__((ext_vector_type(16)));
typedef unsigned u32x4 __attribute__((ext_vector_type(4)));
static_assert(sizeof(bf16x8) == 16, "bf16x8 must be 16B");

// K tile (per 32 kv): 32 rows x 264 ushorts (256 data + 8 pad) = 8704 ushorts.
// V tile (per 32 kv): 256 c x 40 ushorts (32 data + 8 pad) = 10240 ushorts.
constexpr int KTILE = 8704;    // ushorts
constexpr int VTILE = 10240;   // ushorts
constexpr int KINST = 32 * KTILE;   // 278528
constexpr int VINST = 32 * VTILE;   // 327680

__device__ __forceinline__ ushort f2bf(float x) {
  unsigned u = __builtin_bit_cast(unsigned, x);
  u = (u + 0x7fffu + ((u >> 16) & 1u)) >> 16;   // RNE
  return (ushort)u;
}
__device__ __forceinline__ unsigned packbf(float lo, float hi) {
  return (unsigned)f2bf(lo) | ((unsigned)f2bf(hi) << 16);
}
__device__ __forceinline__ void gload_lds16(const ushort* g, ushort* l) {
  __builtin_amdgcn_global_load_lds(
      (const __attribute__((address_space(1))) void*)g,
      (__attribute__((address_space(3))) void*)l, 16, 0, 0);
}

// ---------------------------------------------------------------------------
// Weight conversion: 8 matrices of 131072 f32 -> bf16, vectorized x4.
// ---------------------------------------------------------------------------
struct WcvtArgs { const float* src[8]; };
__global__ __launch_bounds__(256) void wcvt8_k(WcvtArgs a, ushort* __restrict__ dst) {
  const int which = blockIdx.y;
  const int i = (blockIdx.x * 256 + threadIdx.x) * 4;
  float4 x = *reinterpret_cast<const float4*>(a.src[which] + i);
  ushort4 u = {f2bf(x.x), f2bf(x.y), f2bf(x.z), f2bf(x.w)};
  *reinterpret_cast<ushort4*>(dst + (size_t)which * 131072 + i) = u;
}

// ---------------------------------------------------------------------------
// Fused dual-BN transpose, vectorized (round-12, passing).
// ---------------------------------------------------------------------------
__global__ __launch_bounds__(256) void bn2_k(
    const float* __restrict__ rgb, const float* __restrict__ flow,
    const float* __restrict__ g1, const float* __restrict__ b1,
    const float* __restrict__ m1, const float* __restrict__ v1,
    const float* __restrict__ g2, const float* __restrict__ b2,
    const float* __restrict__ m2, const float* __restrict__ v2,
    ushort* __restrict__ Abn1, ushort* __restrict__ Bbn1,
    ushort* __restrict__ Abn2, ushort* __restrict__ Bbn2)
{
  const int z = blockIdx.z;
  const int b = z >> 1, which = z & 1;
  const float* src = which ? flow : rgb;
  ushort* o1 = which ? Bbn1 : Abn1;
  ushort* o2 = which ? Abn2 : Bbn2;
  src += (size_t)b * 512 * 1024;
  o1  += (size_t)b * 1024 * 512;
  o2  += (size_t)b * 1024 * 512;

  __shared__ unsigned tileU[32][36];   // [c-local][n-local], packed bn1|bn2<<16
  const int n0 = blockIdx.x * 32, c0 = blockIdx.y * 32;

  const int rc = threadIdx.x >> 3, nq = threadIdx.x & 7;
  {
    const int c = c0 + rc;
    const float s1 = g1[c] * rsqrtf(v1[c] + 1e-5f);
    const float h1 = b1[c] - m1[c] * s1;
    const float s2 = g2[c] * rsqrtf(v2[c] + 1e-5f);
    const float h2 = b2[c] - m2[c] * s2;
    float4 x = *reinterpret_cast<const float4*>(src + (size_t)c * 1024 + n0 + nq * 4);
    u32x4 u;
    u[0] = packbf(fmaxf(x.x * s1 + h1, 0.f), fmaxf(x.x * s2 + h2, 0.f));
    u[1] = packbf(fmaxf(x.y * s1 + h1, 0.f), fmaxf(x.y * s2 + h2, 0.f));
    u[2] = packbf(fmaxf(x.z * s1 + h1, 0.f), fmaxf(x.z * s2 + h2, 0.f));
    u[3] = packbf(fmaxf(x.w * s1 + h1, 0.f), fmaxf(x.w * s2 + h2, 0.f));
    *reinterpret_cast<u32x4*>(&tileU[rc][nq * 4]) = u;
  }
  __syncthreads();
  const int r = threadIdx.x >> 3, cq = threadIdx.x & 7;
  ushort4 w1, w2;
  {
    const unsigned u0 = tileU[cq * 4 + 0][r];
    const unsigned u1 = tileU[cq * 4 + 1][r];
    const unsigned u2 = tileU[cq * 4 + 2][r];
    const unsigned u3 = tileU[cq * 4 + 3][r];
    w1 = (ushort4){(ushort)(u0 & 0xffff), (ushort)(u1 & 0xffff),
                   (ushort)(u2 & 0xffff), (ushort)(u3 & 0xffff)};
    w2 = (ushort4){(ushort)(u0 >> 16), (ushort)(u1 >> 16),
                   (ushort)(u2 >> 16), (ushort)(u3 >> 16)};
  }
  const size_t base = (size_t)(n0 + r) * 512 + c0 + cq * 4;
  *reinterpret_cast<ushort4*>(o1 + base) = w1;
  *reinterpret_cast<ushort4*>(o2 + base) = w2;
}

// ---------------------------------------------------------------------------
// Unified projection GEMM, 128x128 tile, global_load_lds staging.
// LDS tile layout unchanged (128 rows x 80 ushorts, conflict-free); staged as
// 20 linear 1KB chunks whose per-lane GLOBAL source gathers (row=off/80,
// col=off%80; pad cols load col 0 and are never read). 2 barriers/K-step.
// mode 0: theta -> out[n*256+m]; mode 1: phi -> Kg; mode 2: g -> Vg.
// ---------------------------------------------------------------------------
struct ProjDesc { const ushort* W; const ushort* act; const float* bias;
                  ushort* out; int mode; };
struct ProjArgs { ProjDesc d[6]; };

__global__ __launch_bounds__(256, 4) void proj128_k(ProjArgs pa) {
  __shared__ __align__(16) ushort Al[128 * 80];
  __shared__ __align__(16) ushort Bl[128 * 80];

  const int bx = blockIdx.x;
  const int mb = bx >> 3, nb = bx & 7;
  const int by = blockIdx.y;
  const ProjDesc d = pa.d[by >> 4];
  const int inst = by & 15;
  const ushort* A = d.W;
  const ushort* Bact = d.act + (size_t)inst * 524288;

  const int tid = threadIdx.x;
  const int w = tid >> 6, lane = tid & 63;
  const int q = lane >> 4, lm = lane & 15;
  const int m0 = mb * 128, n0 = nb * 128;

  // Staging geometry: waves 0,1 -> A chunks (j = (w&1)*10 + i);
  //                   waves 2,3 -> B chunks. Global row stride = 512 ushorts.
  const bool isA = (w < 2);
  const ushort* gbase = isA ? (A + (size_t)m0 * 512) : (Bact + (size_t)n0 * 512);
  ushort* lbase = (isA ? Al : Bl) + ((w & 1) * 10) * 512;
  int roff[10];
  #pragma unroll
  for (int i = 0; i < 10; ++i) {
    const int j = (w & 1) * 10 + i;
    const int off = j * 512 + lane * 8;
    const int row = off / 80;
    int col = off - row * 80;
    if (col >= 64) col = 0;           // pad piece: load harmless data
    roff[i] = row * 512 + col;
  }
  auto stage = [&](int kk) {
    #pragma unroll
    for (int i = 0; i < 10; ++i)
      gload_lds16(gbase + roff[i] + kk, lbase + i * 512);
  };

  f32x4 acc[4][4];
  #pragma unroll
  for (int i = 0; i < 4; ++i)
    #pragma unroll
    for (int j = 0; j < 4; ++j) acc[i][j] = (f32x4){0.f, 0.f, 0.f, 0.f};

  const int wm = (w >> 1) * 64, wn = (w & 1) * 64;

  stage(0);
  asm volatile("s_waitcnt vmcnt(0)" ::: "memory");
  __syncthreads();

  for (int t = 0; t < 8; ++t) {
    #pragma unroll
    for (int ks = 0; ks < 2; ++ks) {
      bf16x8 af[4], bfr[4];
      #pragma unroll
      for (int f = 0; f < 4; ++f)
        af[f] = *reinterpret_cast<const bf16x8*>(Al + (wm + f * 16 + lm) * 80 + ks * 32 + q * 8);
      #pragma unroll
      for (int f = 0; f < 4; ++f)
        bfr[f] = *reinterpret_cast<const bf16x8*>(Bl + (wn + f * 16 + lm) * 80 + ks * 32 + q * 8);
      __builtin_amdgcn_s_setprio(1);
      #pragma unroll
      for (int fi = 0; fi < 4; ++fi)
        #pragma unroll
        for (int fj = 0; fj < 4; ++fj)
          acc[fi][fj] = __builtin_amdgcn_mfma_f32_16x16x32_bf16(af[fi], bfr[fj], acc[fi][fj], 0, 0, 0);
      __builtin_amdgcn_s_setprio(0);
    }
    if (t < 7) {
      __syncthreads();                 // all waves done reading tile t
      stage((t + 1) * 64);
      asm volatile("s_waitcnt vmcnt(0)" ::: "memory");
      __syncthreads();                 // tile t+1 visible
    }
  }

  if (d.mode == 0) {
    ushort* out = d.out + (size_t)inst * 262144;
    #pragma unroll
    for (int fi = 0; fi < 4; ++fi)
      #pragma unroll
      for (int fj = 0; fj < 4; ++fj) {
        const int m4 = m0 + wm + fi * 16 + q * 4;
        const int n  = n0 + wn + fj * 16 + lm;
        float4 bi = *reinterpret_cast<const float4*>(d.bias + m4);
        ushort4 u = {f2bf(acc[fi][fj][0] + bi.x), f2bf(acc[fi][fj][1] + bi.y),
                     f2bf(acc[fi][fj][2] + bi.z), f2bf(acc[fi][fj][3] + bi.w)};
        *reinterpret_cast<ushort4*>(out + (size_t)n * 256 + m4) = u;
      }
  } else if (d.mode == 1) {
    // Kg: ushort index = (n>>5)*KTILE + (n&31)*264 + m
    ushort* out = d.out + (size_t)inst * KINST;
    #pragma unroll
    for (int fi = 0; fi < 4; ++fi)
      #pragma unroll
      for (int fj = 0; fj < 4; ++fj) {
        const int m4 = m0 + wm + fi * 16 + q * 4;
        const int n  = n0 + wn + fj * 16 + lm;
        float4 bi = *reinterpret_cast<const float4*>(d.bias + m4);
        ushort4 u = {f2bf(acc[fi][fj][0] + bi.x), f2bf(acc[fi][fj][1] + bi.y),
                     f2bf(acc[fi][fj][2] + bi.z), f2bf(acc[fi][fj][3] + bi.w)};
        *reinterpret_cast<ushort4*>(out + (size_t)(n >> 5) * KTILE + (n & 31) * 264 + m4) = u;
      }
  } else {
    // Vg: ushort index = (n>>5)*VTILE + m*40 + ((n&31)>>3)*8 + (n&7)
    ushort* out = d.out + (size_t)inst * VINST;
    #pragma unroll
    for (int fi = 0; fi < 4; ++fi)
      #pragma unroll
      for (int fj = 0; fj < 4; ++fj) {
        const int n = n0 + wn + fj * 16 + lm;
        const size_t base = (size_t)(n >> 5) * VTILE + ((n & 31) >> 3) * 8 + (n & 7);
        #pragma unroll
        for (int j = 0; j < 4; ++j) {
          const int m = m0 + wm + fi * 16 + q * 4 + j;
          out[base + (size_t)m * 40] = f2bf(acc[fi][fj][j] + d.bias[m]);
        }
      }
  }
}

// ---------------------------------------------------------------------------
// Flash attention — round-6 kernel (single S chain, setprio). [byte-identical]
// ---------------------------------------------------------------------------
__global__ __launch_bounds__(256, 2) void flash_k(
    const ushort* __restrict__ Qp, const ushort* __restrict__ Kg,
    const ushort* __restrict__ Vg, ushort* __restrict__ Op)
{
  __shared__ __align__(16) ushort KV[2][KTILE + VTILE];  // 2 x 37888B
  __shared__ float2 stat2[2][32];

  const int raw = blockIdx.x;
  const int xcd = raw & 7, loc = raw >> 3;
  const int inst = xcd * 4 + (loc >> 4);   // each XCD owns 4 instances
  const int qb = loc & 15;

  const int tid = threadIdx.x;
  const int w = tid >> 6, lane = tid & 63;
  const int u = w & 1, p = w >> 1;
  const int h = lane >> 5, lm5 = lane & 31;

  const ushort* Q  = Qp + (size_t)inst * 262144;
  const ushort* Kt = Kg + (size_t)inst * KINST + (size_t)p * 16 * KTILE;
  const ushort* Vt = Vg + (size_t)inst * VINST + (size_t)p * 16 * VTILE;

  ushort* Klds = &KV[p][0];
  ushort* Vlds = &KV[p][KTILE];

  const int nrow0 = qb * 64 + u * 32;

  bf16x8 qf[16];
  #pragma unroll
  for (int cs = 0; cs < 16; ++cs)
    qf[cs] = *reinterpret_cast<const bf16x8*>(
        Q + (size_t)(nrow0 + lm5) * 256 + cs * 16 + h * 8);

  f32x16 acc[8];
  #pragma unroll
  for (int cb = 0; cb < 8; ++cb)
    #pragma unroll
    for (int i = 0; i < 16; ++i) acc[cb][i] = 0.f;

  float run_m = -__builtin_inff();
  float run_l = 0.f;

  auto stageK = [&](int t) {
    const ushort* src = Kt + (size_t)t * KTILE;
    const int base = u ? 9 : 0;
    #pragma unroll
    for (int j = 0; j < 9; ++j)
      if (u == 0 || j < 8)
        gload_lds16(src + (base + j) * 512 + lane * 8, Klds + (base + j) * 512);
  };
  auto stageV = [&](int t) {
    const ushort* src = Vt + (size_t)t * VTILE;
    #pragma unroll
    for (int j = 0; j < 10; ++j)
      gload_lds16(src + (u * 10 + j) * 512 + lane * 8, Vlds + (u * 10 + j) * 512);
  };

  stageK(0);
  stageV(0);
  asm volatile("s_waitcnt vmcnt(0)" ::: "memory");
  __builtin_amdgcn_sched_barrier(0);
  __builtin_amdgcn_s_barrier();

  for (int t = 0; t < 16; ++t) {
    // ---- QK^T: S[kv=(r&3)+8*(r>>2)+4h][q=lm5]
    f32x16 S;
    #pragma unroll
    for (int i = 0; i < 16; ++i) S[i] = 0.f;
    __builtin_amdgcn_s_setprio(1);
    #pragma unroll
    for (int cs = 0; cs < 16; ++cs) {
      bf16x8 kf = *reinterpret_cast<const bf16x8*>(
          Klds + lm5 * 264 + (cs * 2 + h) * 8);
      S = __builtin_amdgcn_mfma_f32_32x32x16_bf16(kf, qf[cs], S, 0, 0, 0);
    }
    __builtin_amdgcn_s_setprio(0);

    // V(t) has landed (issued last iter; covered by QK); barrier A.
    __builtin_amdgcn_sched_barrier(0);
    asm volatile("s_waitcnt vmcnt(0)" ::: "memory");
    __builtin_amdgcn_sched_barrier(0);
    __builtin_amdgcn_s_barrier();          // A: Klds(t) free, Vlds(t) visible
    __builtin_amdgcn_sched_barrier(0);
    if (t < 15) stageK(t + 1);             // K(t+1) hides under softmax+PV

    // ---- online softmax (per-lane stats; cross-half via shfl_xor 32)
    float ml = fmaxf(fmaxf(fmaxf(S[0], S[1]), fmaxf(S[2], S[3])),
                     fmaxf(fmaxf(S[4], S[5]), fmaxf(S[6], S[7])));
    ml = fmaxf(ml, fmaxf(fmaxf(fmaxf(S[8], S[9]), fmaxf(S[10], S[11])),
                         fmaxf(fmaxf(S[12], S[13]), fmaxf(S[14], S[15]))));
    ml = fmaxf(ml, __shfl_xor(ml, 32));
    const float mnew = fmaxf(run_m, ml);
    if (!__all(ml <= run_m + 8.f)) {      // defer-max
      const float sc = __expf(run_m - mnew);
      run_m = mnew;
      run_l *= sc;
      #pragma unroll
      for (int cb = 0; cb < 8; ++cb) acc[cb] *= sc;
    }
    #pragma unroll
    for (int i = 0; i < 16; ++i) S[i] = __expf(S[i] - run_m);
    float ts = ((S[0] + S[1]) + (S[2] + S[3])) + ((S[4] + S[5]) + (S[6] + S[7]));
    ts += ((S[8] + S[9]) + (S[10] + S[11])) + ((S[12] + S[13]) + (S[14] + S[15]));
    ts += __shfl_xor(ts, 32);
    run_l += ts;

    // ---- pack P to bf16 pairs; partner values via shfl_xor 32
    const unsigned pk0 = packbf(S[0], S[1]),   pk1 = packbf(S[2], S[3]);
    const unsigned pk2 = packbf(S[4], S[5]),   pk3 = packbf(S[6], S[7]);
    const unsigned pk4 = packbf(S[8], S[9]),   pk5 = packbf(S[10], S[11]);
    const unsigned pk6 = packbf(S[12], S[13]), pk7 = packbf(S[14], S[15]);
    const unsigned sx0 = __shfl_xor(pk0, 32), sx1 = __shfl_xor(pk1, 32);
    const unsigned sx2 = __shfl_xor(pk2, 32), sx3 = __shfl_xor(pk3, 32);
    const unsigned sx4 = __shfl_xor(pk4, 32), sx5 = __shfl_xor(pk5, 32);
    const unsigned sx6 = __shfl_xor(pk6, 32), sx7 = __shfl_xor(pk7, 32);
    const bool hh = (h != 0);
    u32x4 B0, B1;
    B0[0] = hh ? sx2 : pk0;  B0[1] = hh ? sx3 : pk1;
    B0[2] = hh ? pk2 : sx0;  B0[3] = hh ? pk3 : sx1;
    B1[0] = hh ? sx6 : pk4;  B1[1] = hh ? sx7 : pk5;
    B1[2] = hh ? pk6 : sx4;  B1[3] = hh ? pk7 : sx5;
    const bf16x8 pf0 = __builtin_bit_cast(bf16x8, B0);
    const bf16x8 pf1 = __builtin_bit_cast(bf16x8, B1);

    // ---- PV: acc[cb] += V^T(c rows) x P   (v0: kv 0-15, v1: kv 16-31)
    __builtin_amdgcn_s_setprio(1);
    #pragma unroll
    for (int cb = 0; cb < 8; ++cb) {
      bf16x8 v0 = *reinterpret_cast<const bf16x8*>(
          Vlds + (cb * 32 + lm5) * 40 + h * 8);
      bf16x8 v1 = *reinterpret_cast<const bf16x8*>(
          Vlds + (cb * 32 + lm5) * 40 + (2 + h) * 8);
      acc[cb] = __builtin_amdgcn_mfma_f32_32x32x16_bf16(v0, pf0, acc[cb], 0, 0, 0);
      acc[cb] = __builtin_amdgcn_mfma_f32_32x32x16_bf16(v1, pf1, acc[cb], 0, 0, 0);
    }
    __builtin_amdgcn_s_setprio(0);

    __builtin_amdgcn_sched_barrier(0);
    __builtin_amdgcn_s_barrier();          // B: Vlds(t) free
    __builtin_amdgcn_sched_barrier(0);
    if (t < 15) {
      stageV(t + 1);                       // V(t+1) hides under next QK
      asm volatile("s_waitcnt vmcnt(10)" ::: "memory");  // K(t+1) done, V in flight
    } else {
      asm volatile("s_waitcnt vmcnt(0)" ::: "memory");
    }
    __builtin_amdgcn_sched_barrier(0);
    __builtin_amdgcn_s_barrier();          // C: Klds(t+1) visible
    __builtin_amdgcn_sched_barrier(0);
  }

  // ---- pair merge (p=1 -> LDS -> p=0 combines) and bf16 store
  __syncthreads();
  if (p == 1 && lane < 32) stat2[u][lm5] = make_float2(run_m, run_l);

  float a0 = 1.f, a1 = 0.f, inv = 1.f;
  float4* mb = reinterpret_cast<float4*>(&KV[0][0]);
  #pragma unroll
  for (int half = 0; half < 2; ++half) {
    __syncthreads();
    if (p == 1) {
      #pragma unroll
      for (int cb2 = 0; cb2 < 4; ++cb2) {
        const int cb = half * 4 + cb2;
        #pragma unroll
        for (int r4 = 0; r4 < 4; ++r4) {
          float4 v = {acc[cb][r4 * 4 + 0], acc[cb][r4 * 4 + 1],
                      acc[cb][r4 * 4 + 2], acc[cb][r4 * 4 + 3]};
          mb[u * 1024 + cb2 * 256 + r4 * 64 + lane] = v;
        }
      }
    }
    __syncthreads();
    if (p == 0) {
      if (half == 0) {
        const float2 s1 = stat2[u][lm5];
        const float M = fmaxf(run_m, s1.x);
        a0 = __expf(run_m - M);
        a1 = __expf(s1.x - M);
        inv = 1.f / (a0 * run_l + a1 * s1.y);
      }
      ushort* Ob = Op + (size_t)inst * 262144 + (size_t)(nrow0 + lm5) * 256;
      #pragma unroll
      for (int cb2 = 0; cb2 < 4; ++cb2) {
        const int cb = half * 4 + cb2;
        #pragma unroll
        for (int r4 = 0; r4 < 4; ++r4) {
          float4 o = mb[u * 1024 + cb2 * 256 + r4 * 64 + lane];
          ushort4 s;
          s.x = f2bf((a0 * acc[cb][r4 * 4 + 0] + a1 * o.x) * inv);
          s.y = f2bf((a0 * acc[cb][r4 * 4 + 1] + a1 * o.y) * inv);
          s.z = f2bf((a0 * acc[cb][r4 * 4 + 2] + a1 * o.z) * inv);
          s.w = f2bf((a0 * acc[cb][r4 * 4 + 3] + a1 * o.w) * inv);
          *reinterpret_cast<ushort4*>(Ob + cb * 32 + r4 * 8 + h * 4) = s;
        }
      }
    }
  }
}

// ---------------------------------------------------------------------------
// W-projection GEMM with fused BN-residual epilogue, global_load_lds staging.
// Same gather-staging as proj128 but K=256 (global row stride 256), 4 K-steps.
// ---------------------------------------------------------------------------
struct WgemmArgs {
  const ushort* yb[2]; const ushort* wW[2]; const float* wb[2];
  const float* src[2]; const float* g[2]; const float* bb[2];
  const float* mm[2]; const float* vv[2];
};

__global__ __launch_bounds__(256, 4) void wgemm_epi_k(WgemmArgs a, float* __restrict__ outp) {
  __shared__ __align__(16) ushort Al[128 * 80];
  __shared__ __align__(16) ushort Bl[128 * 80];

  const int bx = blockIdx.x;
  const int mb = bx >> 2, nb = bx & 3;      // 8 n-blocks x 4 c-blocks
  const int by = blockIdx.y;
  const int mod = by >> 4, b = by & 15;

  const ushort* A  = a.yb[mod] + (size_t)b * 262144;   // rows n, K=256
  const ushort* Bw = a.wW[mod];                         // rows c, K=256
  const float* wb  = a.wb[mod];
  const float* src = a.src[mod] + (size_t)b * 512 * 1024;
  const float* g   = a.g[mod];
  const float* bbp = a.bb[mod];
  const float* mm  = a.mm[mod];
  const float* vv  = a.vv[mod];
  float* out = outp + (size_t)mod * 16 * 512 * 1024 + (size_t)b * 512 * 1024;

  const int tid = threadIdx.x;
  const int w = tid >> 6, lane = tid & 63;
  const int q = lane >> 4, lm = lane & 15;
  const int m0 = mb * 128, n0 = nb * 128;   // m0: n-dim base, n0: c-dim base

  const bool isA = (w < 2);
  const ushort* gbase = isA ? (A + (size_t)m0 * 256) : (Bw + (size_t)n0 * 256);
  ushort* lbase = (isA ? Al : Bl) + ((w & 1) * 10) * 512;
  int roff[10];
  #pragma unroll
  for (int i = 0; i < 10; ++i) {
    const int j = (w & 1) * 10 + i;
    const int off = j * 512 + lane * 8;
    const int row = off / 80;
    int col = off - row * 80;
    if (col >= 64) col = 0;
    roff[i] = row * 256 + col;
  }
  auto stage = [&](int kk) {
    #pragma unroll
    for (int i = 0; i < 10; ++i)
      gload_lds16(gbase + roff[i] + kk, lbase + i * 512);
  };

  f32x4 acc[4][4];
  #pragma unroll
  for (int i = 0; i < 4; ++i)
    #pragma unroll
    for (int j = 0; j < 4; ++j) acc[i][j] = (f32x4){0.f, 0.f, 0.f, 0.f};

  const int wm = (w >> 1) * 64, wn = (w & 1) * 64;

  stage(0);
  asm volatile("s_waitcnt vmcnt(0)" ::: "memory");
  __syncthreads();

  for (int t = 0; t < 4; ++t) {
    #pragma unroll
    for (int ks = 0; ks < 2; ++ks) {
      bf16x8 af[4], bfr[4];
      #pragma unroll
      for (int f = 0; f < 4; ++f)
        af[f] = *reinterpret_cast<const bf16x8*>(Al + (wm + f * 16 + lm) * 80 + ks * 32 + q * 8);
      #pragma unroll
      for (int f = 0; f < 4; ++f)
        bfr[f] = *reinterpret_cast<const bf16x8*>(Bl + (wn + f * 16 + lm) * 80 + ks * 32 + q * 8);
      __builtin_amdgcn_s_setprio(1);
      #pragma unroll
      for (int fi = 0; fi < 4; ++fi)
        #pragma unroll
        for (int fj = 0; fj < 4; ++fj)
          acc[fi][fj] = __builtin_amdgcn_mfma_f32_16x16x32_bf16(af[fi], bfr[fj], acc[fi][fj], 0, 0, 0);
      __builtin_amdgcn_s_setprio(0);
    }
    if (t < 3) {
      __syncthreads();
      stage((t + 1) * 64);
      asm volatile("s_waitcnt vmcnt(0)" ::: "memory");
      __syncthreads();
    }
  }

  #pragma unroll
  for (int fj = 0; fj < 4; ++fj) {
    const int c = n0 + wn + fj * 16 + lm;
    const float sc = g[c] * rsqrtf(vv[c] + 1e-5f);
    const float sh = bbp[c] - mm[c] * sc;
    const float bv = wb[c];
    #pragma unroll
    for (int fi = 0; fi < 4; ++fi) {
      const int n4 = m0 + wm + fi * 16 + q * 4;
      const size_t base = (size_t)c * 1024 + n4;
      float4 x = *reinterpret_cast<const float4*>(src + base);
      float4 v;
      v.x = acc[fi][fj][0] + bv + fmaxf(x.x * sc + sh, 0.f);
      v.y = acc[fi][fj][1] + bv + fmaxf(x.y * sc + sh, 0.f);
      v.z = acc[fi][fj][2] + bv + fmaxf(x.z * sc + sh, 0.f);
      v.w = acc[fi][fj][3] + bv + fmaxf(x.w * sc + sh, 0.f);
      *reinterpret_cast<float4*>(out + base) = v;
    }
  }
}

// ---------------------------------------------------------------------------
// Workspace layout (bytes), ~136 MB.
// ---------------------------------------------------------------------------
constexpr size_t MB = 1ull << 20;
constexpr size_t OFF_WBF = 0;          // 2 MB: [2][4][131072] bf16
constexpr size_t OFF_BN  = 2 * MB;     // 64 MB: Abn1/Bbn1/Abn2/Bbn2
constexpr size_t OFF_TH  = 66 * MB;    // 16 MB [32 inst][1024][256]
constexpr size_t OFF_KG  = 82 * MB;    // 17 MB [32 inst][KINST]
constexpr size_t OFF_VG  = 100 * MB;   // 20 MB [32 inst][VINST]
constexpr size_t OFF_YB  = 120 * MB;   // 16 MB [32 inst][1024][256]

extern "C" void kernel_launch(void* const* d_in, const int* in_sizes, int n_in,
                              void* d_out, int out_size, void* d_ws, size_t ws_size,
                              hipStream_t stream) {
  const float* rgb  = (const float*)d_in[0];
  const float* flow = (const float*)d_in[1];
  auto in = [&](int mod, int j) { return (const float*)d_in[2 + mod * 12 + j]; };
  // j: 0 bn_g, 1 bn_b, 2 bn_m, 3 bn_v, 4 th_w, 5 th_b, 6 ph_w, 7 ph_b,
  //    8 g_w, 9 g_b, 10 w_w, 11 w_b

  char* ws = (char*)d_ws;
  ushort* wbf  = (ushort*)(ws + OFF_WBF);
  ushort* Abn1 = (ushort*)(ws + OFF_BN);
  ushort* Bbn1 = (ushort*)(ws + OFF_BN + 16 * MB);
  ushort* Abn2 = (ushort*)(ws + OFF_BN + 32 * MB);
  ushort* Bbn2 = (ushort*)(ws + OFF_BN + 48 * MB);
  ushort* th   = (ushort*)(ws + OFF_TH);
  ushort* Kgx  = (ushort*)(ws + OFF_KG);
  ushort* Vgx  = (ushort*)(ws + OFF_VG);
  ushort* yb   = (ushort*)(ws + OFF_YB);
  float*  out  = (float*)d_out;

  const size_t MODSTR = (size_t)16 * 262144;

  // 1) weights -> bf16 (vectorized x4)
  WcvtArgs wa;
  for (int mod = 0; mod < 2; ++mod) {
    wa.src[mod * 4 + 0] = in(mod, 4);
    wa.src[mod * 4 + 1] = in(mod, 6);
    wa.src[mod * 4 + 2] = in(mod, 8);
    wa.src[mod * 4 + 3] = in(mod, 10);
  }
  wcvt8_k<<<dim3(128, 8), 256, 0, stream>>>(wa, wbf);

  // 2) fused dual-BN transpose (vectorized)
  bn2_k<<<dim3(32, 16, 32), 256, 0, stream>>>(
      rgb, flow,
      in(0, 0), in(0, 1), in(0, 2), in(0, 3),
      in(1, 0), in(1, 1), in(1, 2), in(1, 3),
      Abn1, Bbn1, Abn2, Bbn2);

  // 3) all six projections, one launch
  ProjArgs pa;
  for (int mod = 0; mod < 2; ++mod) {
    const ushort* wb4 = wbf + (size_t)mod * 4 * 131072;
    ushort* Abn = mod ? Abn2 : Abn1;
    ushort* Bbn = mod ? Bbn2 : Bbn1;
    pa.d[mod * 3 + 0] = {wb4,              Abn, in(mod, 5), th + mod * MODSTR,               0};
    pa.d[mod * 3 + 1] = {wb4 + 131072,     Bbn, in(mod, 7), Kgx + (size_t)mod * 16 * KINST, 1};
    pa.d[mod * 3 + 2] = {wb4 + 2 * 131072, Abn, in(mod, 9), Vgx + (size_t)mod * 16 * VINST, 2};
  }
  proj128_k<<<dim3(16, 96), 256, 0, stream>>>(pa);

  // 4) flash attention (both modules, in-block KV-split, XCD-chunked)
  flash_k<<<dim3(512), 256, 0, stream>>>(th, Kgx, Vgx, yb);

  // 5) W-projection + BN-residual epilogue, both modules in one launch
  WgemmArgs ga;
  for (int mod = 0; mod < 2; ++mod) {
    ga.yb[mod]  = yb + mod * MODSTR;
    ga.wW[mod]  = wbf + (size_t)(mod * 4 + 3) * 131072;
    ga.wb[mod]  = in(mod, 11);
    ga.src[mod] = mod ? flow : rgb;
    ga.g[mod]   = in(mod, 0);
    ga.bb[mod]  = in(mod, 1);
    ga.mm[mod]  = in(mod, 2);
    ga.vv[mod]  = in(mod, 3);
  }
  wgemm_epi_k<<<dim3(32, 32), 256, 0, stream>>>(ga, out);
}

// Round 15
// 167.967 us; speedup vs baseline: 1.0439x; 1.0439x over previous
//
#include <hip/hip_runtime.h>

// ---------------------------------------------------------------------------
// Mutual Feature Refinement — round 15 (= round 13, the session best).
// Round-14 post-mortem: gather-source global_load_lds staging for proj/wgemm
// regressed (+7 µs; gather breaks coalescing at 80-ushort row boundaries and
// the vmcnt(0)-drain schedule serialized what reg-staging already pipelined).
// Reverted to round-13 reg-staged proj128/wgemm. flash_k = round-6 form.
// ---------------------------------------------------------------------------

typedef __bf16 bf16x8 __attribute__((ext_vector_type(8)));
typedef float  f32x4  __attribute__((ext_vector_type(4)));
typedef float  f32x16 __attribute__((ext_vector_type(16)));
typedef unsigned u32x4 __attribute__((ext_vector_type(4)));
static_assert(sizeof(bf16x8) == 16, "bf16x8 must be 16B");

// K tile (per 32 kv): 32 rows x 264 ushorts (256 data + 8 pad) = 8704 ushorts.
// V tile (per 32 kv): 256 c x 40 ushorts (32 data + 8 pad) = 10240 ushorts.
constexpr int KTILE = 8704;    // ushorts
constexpr int VTILE = 10240;   // ushorts
constexpr int KINST = 32 * KTILE;   // 278528
constexpr int VINST = 32 * VTILE;   // 327680

__device__ __forceinline__ ushort f2bf(float x) {
  unsigned u = __builtin_bit_cast(unsigned, x);
  u = (u + 0x7fffu + ((u >> 16) & 1u)) >> 16;   // RNE
  return (ushort)u;
}
__device__ __forceinline__ unsigned packbf(float lo, float hi) {
  return (unsigned)f2bf(lo) | ((unsigned)f2bf(hi) << 16);
}
__device__ __forceinline__ void gload_lds16(const ushort* g, ushort* l) {
  __builtin_amdgcn_global_load_lds(
      (const __attribute__((address_space(1))) void*)g,
      (__attribute__((address_space(3))) void*)l, 16, 0, 0);
}

// ---------------------------------------------------------------------------
// Weight conversion: 8 matrices of 131072 f32 -> bf16, vectorized x4.
// ---------------------------------------------------------------------------
struct WcvtArgs { const float* src[8]; };
__global__ __launch_bounds__(256) void wcvt8_k(WcvtArgs a, ushort* __restrict__ dst) {
  const int which = blockIdx.y;
  const int i = (blockIdx.x * 256 + threadIdx.x) * 4;
  float4 x = *reinterpret_cast<const float4*>(a.src[which] + i);
  ushort4 u = {f2bf(x.x), f2bf(x.y), f2bf(x.z), f2bf(x.w)};
  *reinterpret_cast<ushort4*>(dst + (size_t)which * 131072 + i) = u;
}

// ---------------------------------------------------------------------------
// Fused dual-BN transpose, vectorized (round-12, passing).
// ---------------------------------------------------------------------------
__global__ __launch_bounds__(256) void bn2_k(
    const float* __restrict__ rgb, const float* __restrict__ flow,
    const float* __restrict__ g1, const float* __restrict__ b1,
    const float* __restrict__ m1, const float* __restrict__ v1,
    const float* __restrict__ g2, const float* __restrict__ b2,
    const float* __restrict__ m2, const float* __restrict__ v2,
    ushort* __restrict__ Abn1, ushort* __restrict__ Bbn1,
    ushort* __restrict__ Abn2, ushort* __restrict__ Bbn2)
{
  const int z = blockIdx.z;
  const int b = z >> 1, which = z & 1;
  const float* src = which ? flow : rgb;
  ushort* o1 = which ? Bbn1 : Abn1;
  ushort* o2 = which ? Abn2 : Bbn2;
  src += (size_t)b * 512 * 1024;
  o1  += (size_t)b * 1024 * 512;
  o2  += (size_t)b * 1024 * 512;

  __shared__ unsigned tileU[32][36];   // [c-local][n-local], packed bn1|bn2<<16
  const int n0 = blockIdx.x * 32, c0 = blockIdx.y * 32;

  const int rc = threadIdx.x >> 3, nq = threadIdx.x & 7;
  {
    const int c = c0 + rc;
    const float s1 = g1[c] * rsqrtf(v1[c] + 1e-5f);
    const float h1 = b1[c] - m1[c] * s1;
    const float s2 = g2[c] * rsqrtf(v2[c] + 1e-5f);
    const float h2 = b2[c] - m2[c] * s2;
    float4 x = *reinterpret_cast<const float4*>(src + (size_t)c * 1024 + n0 + nq * 4);
    u32x4 u;
    u[0] = packbf(fmaxf(x.x * s1 + h1, 0.f), fmaxf(x.x * s2 + h2, 0.f));
    u[1] = packbf(fmaxf(x.y * s1 + h1, 0.f), fmaxf(x.y * s2 + h2, 0.f));
    u[2] = packbf(fmaxf(x.z * s1 + h1, 0.f), fmaxf(x.z * s2 + h2, 0.f));
    u[3] = packbf(fmaxf(x.w * s1 + h1, 0.f), fmaxf(x.w * s2 + h2, 0.f));
    *reinterpret_cast<u32x4*>(&tileU[rc][nq * 4]) = u;
  }
  __syncthreads();
  const int r = threadIdx.x >> 3, cq = threadIdx.x & 7;
  ushort4 w1, w2;
  {
    const unsigned u0 = tileU[cq * 4 + 0][r];
    const unsigned u1 = tileU[cq * 4 + 1][r];
    const unsigned u2 = tileU[cq * 4 + 2][r];
    const unsigned u3 = tileU[cq * 4 + 3][r];
    w1 = (ushort4){(ushort)(u0 & 0xffff), (ushort)(u1 & 0xffff),
                   (ushort)(u2 & 0xffff), (ushort)(u3 & 0xffff)};
    w2 = (ushort4){(ushort)(u0 >> 16), (ushort)(u1 >> 16),
                   (ushort)(u2 >> 16), (ushort)(u3 >> 16)};
  }
  const size_t base = (size_t)(n0 + r) * 512 + c0 + cq * 4;
  *reinterpret_cast<ushort4*>(o1 + base) = w1;
  *reinterpret_cast<ushort4*>(o2 + base) = w2;
}

// ---------------------------------------------------------------------------
// Unified projection GEMM, 128x128 tile, LDS-staged (reg prefetch), one
// launch for all 6. [round-13 kernel, byte-identical]
// ---------------------------------------------------------------------------
struct ProjDesc { const ushort* W; const ushort* act; const float* bias;
                  ushort* out; int mode; };
struct ProjArgs { ProjDesc d[6]; };

__global__ __launch_bounds__(256, 2) void proj128_k(ProjArgs pa) {
  __shared__ __align__(16) ushort Al[128 * 80];
  __shared__ __align__(16) ushort Bl[128 * 80];

  const int bx = blockIdx.x;
  const int mb = bx >> 3, nb = bx & 7;
  const int by = blockIdx.y;
  const ProjDesc d = pa.d[by >> 4];
  const int inst = by & 15;
  const ushort* A = d.W;
  const ushort* Bact = d.act + (size_t)inst * 524288;

  const int tid = threadIdx.x;
  const int w = tid >> 6, lane = tid & 63;
  const int q = lane >> 4, lm = lane & 15;
  const int m0 = mb * 128, n0 = nb * 128;

  int row[4], c8[4];
  #pragma unroll
  for (int i = 0; i < 4; ++i) { int g = i * 256 + tid; row[i] = g >> 3; c8[i] = g & 7; }

  bf16x8 ast[4], bst[4];
  auto sload = [&](int kk) {
    #pragma unroll
    for (int i = 0; i < 4; ++i) {
      ast[i] = *reinterpret_cast<const bf16x8*>(A + (size_t)(m0 + row[i]) * 512 + kk + c8[i] * 8);
      bst[i] = *reinterpret_cast<const bf16x8*>(Bact + (size_t)(n0 + row[i]) * 512 + kk + c8[i] * 8);
    }
  };
  sload(0);

  f32x4 acc[4][4];
  #pragma unroll
  for (int i = 0; i < 4; ++i)
    #pragma unroll
    for (int j = 0; j < 4; ++j) acc[i][j] = (f32x4){0.f, 0.f, 0.f, 0.f};

  const int wm = (w >> 1) * 64, wn = (w & 1) * 64;

  for (int t = 0; t < 8; ++t) {
    __syncthreads();
    #pragma unroll
    for (int i = 0; i < 4; ++i) {
      *reinterpret_cast<bf16x8*>(Al + row[i] * 80 + c8[i] * 8) = ast[i];
      *reinterpret_cast<bf16x8*>(Bl + row[i] * 80 + c8[i] * 8) = bst[i];
    }
    __syncthreads();
    if (t < 7) sload((t + 1) * 64);
    #pragma unroll
    for (int ks = 0; ks < 2; ++ks) {
      bf16x8 af[4], bfr[4];
      #pragma unroll
      for (int f = 0; f < 4; ++f)
        af[f] = *reinterpret_cast<const bf16x8*>(Al + (wm + f * 16 + lm) * 80 + ks * 32 + q * 8);
      #pragma unroll
      for (int f = 0; f < 4; ++f)
        bfr[f] = *reinterpret_cast<const bf16x8*>(Bl + (wn + f * 16 + lm) * 80 + ks * 32 + q * 8);
      __builtin_amdgcn_s_setprio(1);
      #pragma unroll
      for (int fi = 0; fi < 4; ++fi)
        #pragma unroll
        for (int fj = 0; fj < 4; ++fj)
          acc[fi][fj] = __builtin_amdgcn_mfma_f32_16x16x32_bf16(af[fi], bfr[fj], acc[fi][fj], 0, 0, 0);
      __builtin_amdgcn_s_setprio(0);
    }
  }

  if (d.mode == 0) {
    ushort* out = d.out + (size_t)inst * 262144;
    #pragma unroll
    for (int fi = 0; fi < 4; ++fi)
      #pragma unroll
      for (int fj = 0; fj < 4; ++fj) {
        const int m4 = m0 + wm + fi * 16 + q * 4;
        const int n  = n0 + wn + fj * 16 + lm;
        float4 bi = *reinterpret_cast<const float4*>(d.bias + m4);
        ushort4 u = {f2bf(acc[fi][fj][0] + bi.x), f2bf(acc[fi][fj][1] + bi.y),
                     f2bf(acc[fi][fj][2] + bi.z), f2bf(acc[fi][fj][3] + bi.w)};
        *reinterpret_cast<ushort4*>(out + (size_t)n * 256 + m4) = u;
      }
  } else if (d.mode == 1) {
    // Kg: ushort index = (n>>5)*KTILE + (n&31)*264 + m
    ushort* out = d.out + (size_t)inst * KINST;
    #pragma unroll
    for (int fi = 0; fi < 4; ++fi)
      #pragma unroll
      for (int fj = 0; fj < 4; ++fj) {
        const int m4 = m0 + wm + fi * 16 + q * 4;
        const int n  = n0 + wn + fj * 16 + lm;
        float4 bi = *reinterpret_cast<const float4*>(d.bias + m4);
        ushort4 u = {f2bf(acc[fi][fj][0] + bi.x), f2bf(acc[fi][fj][1] + bi.y),
                     f2bf(acc[fi][fj][2] + bi.z), f2bf(acc[fi][fj][3] + bi.w)};
        *reinterpret_cast<ushort4*>(out + (size_t)(n >> 5) * KTILE + (n & 31) * 264 + m4) = u;
      }
  } else {
    // Vg: ushort index = (n>>5)*VTILE + m*40 + ((n&31)>>3)*8 + (n&7)
    ushort* out = d.out + (size_t)inst * VINST;
    #pragma unroll
    for (int fi = 0; fi < 4; ++fi)
      #pragma unroll
      for (int fj = 0; fj < 4; ++fj) {
        const int n = n0 + wn + fj * 16 + lm;
        const size_t base = (size_t)(n >> 5) * VTILE + ((n & 31) >> 3) * 8 + (n & 7);
        #pragma unroll
        for (int j = 0; j < 4; ++j) {
          const int m = m0 + wm + fi * 16 + q * 4 + j;
          out[base + (size_t)m * 40] = f2bf(acc[fi][fj][j] + d.bias[m]);
        }
      }
  }
}

// ---------------------------------------------------------------------------
// Flash attention — round-6 kernel (single S chain, setprio). [byte-identical]
// ---------------------------------------------------------------------------
__global__ __launch_bounds__(256, 2) void flash_k(
    const ushort* __restrict__ Qp, const ushort* __restrict__ Kg,
    const ushort* __restrict__ Vg, ushort* __restrict__ Op)
{
  __shared__ __align__(16) ushort KV[2][KTILE + VTILE];  // 2 x 37888B
  __shared__ float2 stat2[2][32];

  const int raw = blockIdx.x;
  const int xcd = raw & 7, loc = raw >> 3;
  const int inst = xcd * 4 + (loc >> 4);   // each XCD owns 4 instances
  const int qb = loc & 15;

  const int tid = threadIdx.x;
  const int w = tid >> 6, lane = tid & 63;
  const int u = w & 1, p = w >> 1;
  const int h = lane >> 5, lm5 = lane & 31;

  const ushort* Q  = Qp + (size_t)inst * 262144;
  const ushort* Kt = Kg + (size_t)inst * KINST + (size_t)p * 16 * KTILE;
  const ushort* Vt = Vg + (size_t)inst * VINST + (size_t)p * 16 * VTILE;

  ushort* Klds = &KV[p][0];
  ushort* Vlds = &KV[p][KTILE];

  const int nrow0 = qb * 64 + u * 32;

  bf16x8 qf[16];
  #pragma unroll
  for (int cs = 0; cs < 16; ++cs)
    qf[cs] = *reinterpret_cast<const bf16x8*>(
        Q + (size_t)(nrow0 + lm5) * 256 + cs * 16 + h * 8);

  f32x16 acc[8];
  #pragma unroll
  for (int cb = 0; cb < 8; ++cb)
    #pragma unroll
    for (int i = 0; i < 16; ++i) acc[cb][i] = 0.f;

  float run_m = -__builtin_inff();
  float run_l = 0.f;

  auto stageK = [&](int t) {
    const ushort* src = Kt + (size_t)t * KTILE;
    const int base = u ? 9 : 0;
    #pragma unroll
    for (int j = 0; j < 9; ++j)
      if (u == 0 || j < 8)
        gload_lds16(src + (base + j) * 512 + lane * 8, Klds + (base + j) * 512);
  };
  auto stageV = [&](int t) {
    const ushort* src = Vt + (size_t)t * VTILE;
    #pragma unroll
    for (int j = 0; j < 10; ++j)
      gload_lds16(src + (u * 10 + j) * 512 + lane * 8, Vlds + (u * 10 + j) * 512);
  };

  stageK(0);
  stageV(0);
  asm volatile("s_waitcnt vmcnt(0)" ::: "memory");
  __builtin_amdgcn_sched_barrier(0);
  __builtin_amdgcn_s_barrier();

  for (int t = 0; t < 16; ++t) {
    // ---- QK^T: S[kv=(r&3)+8*(r>>2)+4h][q=lm5]
    f32x16 S;
    #pragma unroll
    for (int i = 0; i < 16; ++i) S[i] = 0.f;
    __builtin_amdgcn_s_setprio(1);
    #pragma unroll
    for (int cs = 0; cs < 16; ++cs) {
      bf16x8 kf = *reinterpret_cast<const bf16x8*>(
          Klds + lm5 * 264 + (cs * 2 + h) * 8);
      S = __builtin_amdgcn_mfma_f32_32x32x16_bf16(kf, qf[cs], S, 0, 0, 0);
    }
    __builtin_amdgcn_s_setprio(0);

    // V(t) has landed (issued last iter; covered by QK); barrier A.
    __builtin_amdgcn_sched_barrier(0);
    asm volatile("s_waitcnt vmcnt(0)" ::: "memory");
    __builtin_amdgcn_sched_barrier(0);
    __builtin_amdgcn_s_barrier();          // A: Klds(t) free, Vlds(t) visible
    __builtin_amdgcn_sched_barrier(0);
    if (t < 15) stageK(t + 1);             // K(t+1) hides under softmax+PV

    // ---- online softmax (per-lane stats; cross-half via shfl_xor 32)
    float ml = fmaxf(fmaxf(fmaxf(S[0], S[1]), fmaxf(S[2], S[3])),
                     fmaxf(fmaxf(S[4], S[5]), fmaxf(S[6], S[7])));
    ml = fmaxf(ml, fmaxf(fmaxf(fmaxf(S[8], S[9]), fmaxf(S[10], S[11])),
                         fmaxf(fmaxf(S[12], S[13]), fmaxf(S[14], S[15]))));
    ml = fmaxf(ml, __shfl_xor(ml, 32));
    const float mnew = fmaxf(run_m, ml);
    if (!__all(ml <= run_m + 8.f)) {      // defer-max
      const float sc = __expf(run_m - mnew);
      run_m = mnew;
      run_l *= sc;
      #pragma unroll
      for (int cb = 0; cb < 8; ++cb) acc[cb] *= sc;
    }
    #pragma unroll
    for (int i = 0; i < 16; ++i) S[i] = __expf(S[i] - run_m);
    float ts = ((S[0] + S[1]) + (S[2] + S[3])) + ((S[4] + S[5]) + (S[6] + S[7]));
    ts += ((S[8] + S[9]) + (S[10] + S[11])) + ((S[12] + S[13]) + (S[14] + S[15]));
    ts += __shfl_xor(ts, 32);
    run_l += ts;

    // ---- pack P to bf16 pairs; partner values via shfl_xor 32
    const unsigned pk0 = packbf(S[0], S[1]),   pk1 = packbf(S[2], S[3]);
    const unsigned pk2 = packbf(S[4], S[5]),   pk3 = packbf(S[6], S[7]);
    const unsigned pk4 = packbf(S[8], S[9]),   pk5 = packbf(S[10], S[11]);
    const unsigned pk6 = packbf(S[12], S[13]), pk7 = packbf(S[14], S[15]);
    const unsigned sx0 = __shfl_xor(pk0, 32), sx1 = __shfl_xor(pk1, 32);
    const unsigned sx2 = __shfl_xor(pk2, 32), sx3 = __shfl_xor(pk3, 32);
    const unsigned sx4 = __shfl_xor(pk4, 32), sx5 = __shfl_xor(pk5, 32);
    const unsigned sx6 = __shfl_xor(pk6, 32), sx7 = __shfl_xor(pk7, 32);
    const bool hh = (h != 0);
    u32x4 B0, B1;
    B0[0] = hh ? sx2 : pk0;  B0[1] = hh ? sx3 : pk1;
    B0[2] = hh ? pk2 : sx0;  B0[3] = hh ? pk3 : sx1;
    B1[0] = hh ? sx6 : pk4;  B1[1] = hh ? sx7 : pk5;
    B1[2] = hh ? pk6 : sx4;  B1[3] = hh ? pk7 : sx5;
    const bf16x8 pf0 = __builtin_bit_cast(bf16x8, B0);
    const bf16x8 pf1 = __builtin_bit_cast(bf16x8, B1);

    // ---- PV: acc[cb] += V^T(c rows) x P   (v0: kv 0-15, v1: kv 16-31)
    __builtin_amdgcn_s_setprio(1);
    #pragma unroll
    for (int cb = 0; cb < 8; ++cb) {
      bf16x8 v0 = *reinterpret_cast<const bf16x8*>(
          Vlds + (cb * 32 + lm5) * 40 + h * 8);
      bf16x8 v1 = *reinterpret_cast<const bf16x8*>(
          Vlds + (cb * 32 + lm5) * 40 + (2 + h) * 8);
      acc[cb] = __builtin_amdgcn_mfma_f32_32x32x16_bf16(v0, pf0, acc[cb], 0, 0, 0);
      acc[cb] = __builtin_amdgcn_mfma_f32_32x32x16_bf16(v1, pf1, acc[cb], 0, 0, 0);
    }
    __builtin_amdgcn_s_setprio(0);

    __builtin_amdgcn_sched_barrier(0);
    __builtin_amdgcn_s_barrier();          // B: Vlds(t) free
    __builtin_amdgcn_sched_barrier(0);
    if (t < 15) {
      stageV(t + 1);                       // V(t+1) hides under next QK
      asm volatile("s_waitcnt vmcnt(10)" ::: "memory");  // K(t+1) done, V in flight
    } else {
      asm volatile("s_waitcnt vmcnt(0)" ::: "memory");
    }
    __builtin_amdgcn_sched_barrier(0);
    __builtin_amdgcn_s_barrier();          // C: Klds(t+1) visible
    __builtin_amdgcn_sched_barrier(0);
  }

  // ---- pair merge (p=1 -> LDS -> p=0 combines) and bf16 store
  __syncthreads();
  if (p == 1 && lane < 32) stat2[u][lm5] = make_float2(run_m, run_l);

  float a0 = 1.f, a1 = 0.f, inv = 1.f;
  float4* mb = reinterpret_cast<float4*>(&KV[0][0]);
  #pragma unroll
  for (int half = 0; half < 2; ++half) {
    __syncthreads();
    if (p == 1) {
      #pragma unroll
      for (int cb2 = 0; cb2 < 4; ++cb2) {
        const int cb = half * 4 + cb2;
        #pragma unroll
        for (int r4 = 0; r4 < 4; ++r4) {
          float4 v = {acc[cb][r4 * 4 + 0], acc[cb][r4 * 4 + 1],
                      acc[cb][r4 * 4 + 2], acc[cb][r4 * 4 + 3]};
          mb[u * 1024 + cb2 * 256 + r4 * 64 + lane] = v;
        }
      }
    }
    __syncthreads();
    if (p == 0) {
      if (half == 0) {
        const float2 s1 = stat2[u][lm5];
        const float M = fmaxf(run_m, s1.x);
        a0 = __expf(run_m - M);
        a1 = __expf(s1.x - M);
        inv = 1.f / (a0 * run_l + a1 * s1.y);
      }
      ushort* Ob = Op + (size_t)inst * 262144 + (size_t)(nrow0 + lm5) * 256;
      #pragma unroll
      for (int cb2 = 0; cb2 < 4; ++cb2) {
        const int cb = half * 4 + cb2;
        #pragma unroll
        for (int r4 = 0; r4 < 4; ++r4) {
          float4 o = mb[u * 1024 + cb2 * 256 + r4 * 64 + lane];
          ushort4 s;
          s.x = f2bf((a0 * acc[cb][r4 * 4 + 0] + a1 * o.x) * inv);
          s.y = f2bf((a0 * acc[cb][r4 * 4 + 1] + a1 * o.y) * inv);
          s.z = f2bf((a0 * acc[cb][r4 * 4 + 2] + a1 * o.z) * inv);
          s.w = f2bf((a0 * acc[cb][r4 * 4 + 3] + a1 * o.w) * inv);
          *reinterpret_cast<ushort4*>(Ob + cb * 32 + r4 * 8 + h * 4) = s;
        }
      }
    }
  }
}

// ---------------------------------------------------------------------------
// W-projection GEMM with fused BN-residual epilogue — proj128 structure.
// [round-13 kernel, byte-identical]
// ---------------------------------------------------------------------------
struct WgemmArgs {
  const ushort* yb[2]; const ushort* wW[2]; const float* wb[2];
  const float* src[2]; const float* g[2]; const float* bb[2];
  const float* mm[2]; const float* vv[2];
};

__global__ __launch_bounds__(256, 2) void wgemm_epi_k(WgemmArgs a, float* __restrict__ outp) {
  __shared__ __align__(16) ushort Al[128 * 80];
  __shared__ __align__(16) ushort Bl[128 * 80];

  const int bx = blockIdx.x;
  const int mb = bx >> 2, nb = bx & 3;      // 8 n-blocks x 4 c-blocks
  const int by = blockIdx.y;
  const int mod = by >> 4, b = by & 15;

  const ushort* A  = a.yb[mod] + (size_t)b * 262144;   // rows n, K=256
  const ushort* Bw = a.wW[mod];                         // rows c, K=256
  const float* wb  = a.wb[mod];
  const float* src = a.src[mod] + (size_t)b * 512 * 1024;
  const float* g   = a.g[mod];
  const float* bbp = a.bb[mod];
  const float* mm  = a.mm[mod];
  const float* vv  = a.vv[mod];
  float* out = outp + (size_t)mod * 16 * 512 * 1024 + (size_t)b * 512 * 1024;

  const int tid = threadIdx.x;
  const int w = tid >> 6, lane = tid & 63;
  const int q = lane >> 4, lm = lane & 15;
  const int m0 = mb * 128, n0 = nb * 128;   // m0: n-dim base, n0: c-dim base

  int row[4], c8[4];
  #pragma unroll
  for (int i = 0; i < 4; ++i) { int gg = i * 256 + tid; row[i] = gg >> 3; c8[i] = gg & 7; }

  bf16x8 ast[4], bst[4];
  auto sload = [&](int kk) {
    #pragma unroll
    for (int i = 0; i < 4; ++i) {
      ast[i] = *reinterpret_cast<const bf16x8*>(A  + (size_t)(m0 + row[i]) * 256 + kk + c8[i] * 8);
      bst[i] = *reinterpret_cast<const bf16x8*>(Bw + (size_t)(n0 + row[i]) * 256 + kk + c8[i] * 8);
    }
  };
  sload(0);

  f32x4 acc[4][4];
  #pragma unroll
  for (int i = 0; i < 4; ++i)
    #pragma unroll
    for (int j = 0; j < 4; ++j) acc[i][j] = (f32x4){0.f, 0.f, 0.f, 0.f};

  const int wm = (w >> 1) * 64, wn = (w & 1) * 64;

  for (int t = 0; t < 4; ++t) {
    __syncthreads();
    #pragma unroll
    for (int i = 0; i < 4; ++i) {
      *reinterpret_cast<bf16x8*>(Al + row[i] * 80 + c8[i] * 8) = ast[i];
      *reinterpret_cast<bf16x8*>(Bl + row[i] * 80 + c8[i] * 8) = bst[i];
    }
    __syncthreads();
    if (t < 3) sload((t + 1) * 64);
    #pragma unroll
    for (int ks = 0; ks < 2; ++ks) {
      bf16x8 af[4], bfr[4];
      #pragma unroll
      for (int f = 0; f < 4; ++f)
        af[f] = *reinterpret_cast<const bf16x8*>(Al + (wm + f * 16 + lm) * 80 + ks * 32 + q * 8);
      #pragma unroll
      for (int f = 0; f < 4; ++f)
        bfr[f] = *reinterpret_cast<const bf16x8*>(Bl + (wn + f * 16 + lm) * 80 + ks * 32 + q * 8);
      __builtin_amdgcn_s_setprio(1);
      #pragma unroll
      for (int fi = 0; fi < 4; ++fi)
        #pragma unroll
        for (int fj = 0; fj < 4; ++fj)
          acc[fi][fj] = __builtin_amdgcn_mfma_f32_16x16x32_bf16(af[fi], bfr[fj], acc[fi][fj], 0, 0, 0);
      __builtin_amdgcn_s_setprio(0);
    }
  }

  #pragma unroll
  for (int fj = 0; fj < 4; ++fj) {
    const int c = n0 + wn + fj * 16 + lm;
    const float sc = g[c] * rsqrtf(vv[c] + 1e-5f);
    const float sh = bbp[c] - mm[c] * sc;
    const float bv = wb[c];
    #pragma unroll
    for (int fi = 0; fi < 4; ++fi) {
      const int n4 = m0 + wm + fi * 16 + q * 4;
      const size_t base = (size_t)c * 1024 + n4;
      float4 x = *reinterpret_cast<const float4*>(src + base);
      float4 v;
      v.x = acc[fi][fj][0] + bv + fmaxf(x.x * sc + sh, 0.f);
      v.y = acc[fi][fj][1] + bv + fmaxf(x.y * sc + sh, 0.f);
      v.z = acc[fi][fj][2] + bv + fmaxf(x.z * sc + sh, 0.f);
      v.w = acc[fi][fj][3] + bv + fmaxf(x.w * sc + sh, 0.f);
      *reinterpret_cast<float4*>(out + base) = v;
    }
  }
}

// ---------------------------------------------------------------------------
// Workspace layout (bytes), ~136 MB.
// ---------------------------------------------------------------------------
constexpr size_t MB = 1ull << 20;
constexpr size_t OFF_WBF = 0;          // 2 MB: [2][4][131072] bf16
constexpr size_t OFF_BN  = 2 * MB;     // 64 MB: Abn1/Bbn1/Abn2/Bbn2
constexpr size_t OFF_TH  = 66 * MB;    // 16 MB [32 inst][1024][256]
constexpr size_t OFF_KG  = 82 * MB;    // 17 MB [32 inst][KINST]
constexpr size_t OFF_VG  = 100 * MB;   // 20 MB [32 inst][VINST]
constexpr size_t OFF_YB  = 120 * MB;   // 16 MB [32 inst][1024][256]

extern "C" void kernel_launch(void* const* d_in, const int* in_sizes, int n_in,
                              void* d_out, int out_size, void* d_ws, size_t ws_size,
                              hipStream_t stream) {
  const float* rgb  = (const float*)d_in[0];
  const float* flow = (const float*)d_in[1];
  auto in = [&](int mod, int j) { return (const float*)d_in[2 + mod * 12 + j]; };
  // j: 0 bn_g, 1 bn_b, 2 bn_m, 3 bn_v, 4 th_w, 5 th_b, 6 ph_w, 7 ph_b,
  //    8 g_w, 9 g_b, 10 w_w, 11 w_b

  char* ws = (char*)d_ws;
  ushort* wbf  = (ushort*)(ws + OFF_WBF);
  ushort* Abn1 = (ushort*)(ws + OFF_BN);
  ushort* Bbn1 = (ushort*)(ws + OFF_BN + 16 * MB);
  ushort* Abn2 = (ushort*)(ws + OFF_BN + 32 * MB);
  ushort* Bbn2 = (ushort*)(ws + OFF_BN + 48 * MB);
  ushort* th   = (ushort*)(ws + OFF_TH);
  ushort* Kgx  = (ushort*)(ws + OFF_KG);
  ushort* Vgx  = (ushort*)(ws + OFF_VG);
  ushort* yb   = (ushort*)(ws + OFF_YB);
  float*  out  = (float*)d_out;

  const size_t MODSTR = (size_t)16 * 262144;

  // 1) weights -> bf16 (vectorized x4)
  WcvtArgs wa;
  for (int mod = 0; mod < 2; ++mod) {
    wa.src[mod * 4 + 0] = in(mod, 4);
    wa.src[mod * 4 + 1] = in(mod, 6);
    wa.src[mod * 4 + 2] = in(mod, 8);
    wa.src[mod * 4 + 3] = in(mod, 10);
  }
  wcvt8_k<<<dim3(128, 8), 256, 0, stream>>>(wa, wbf);

  // 2) fused dual-BN transpose (vectorized)
  bn2_k<<<dim3(32, 16, 32), 256, 0, stream>>>(
      rgb, flow,
      in(0, 0), in(0, 1), in(0, 2), in(0, 3),
      in(1, 0), in(1, 1), in(1, 2), in(1, 3),
      Abn1, Bbn1, Abn2, Bbn2);

  // 3) all six projections, one launch
  ProjArgs pa;
  for (int mod = 0; mod < 2; ++mod) {
    const ushort* wb4 = wbf + (size_t)mod * 4 * 131072;
    ushort* Abn = mod ? Abn2 : Abn1;
    ushort* Bbn = mod ? Bbn2 : Bbn1;
    pa.d[mod * 3 + 0] = {wb4,              Abn, in(mod, 5), th + mod * MODSTR,               0};
    pa.d[mod * 3 + 1] = {wb4 + 131072,     Bbn, in(mod, 7), Kgx + (size_t)mod * 16 * KINST, 1};
    pa.d[mod * 3 + 2] = {wb4 + 2 * 131072, Abn, in(mod, 9), Vgx + (size_t)mod * 16 * VINST, 2};
  }
  proj128_k<<<dim3(16, 96), 256, 0, stream>>>(pa);

  // 4) flash attention (both modules, in-block KV-split, XCD-chunked)
  flash_k<<<dim3(512), 256, 0, stream>>>(th, Kgx, Vgx, yb);

  // 5) W-projection + BN-residual epilogue, both modules in one launch
  WgemmArgs ga;
  for (int mod = 0; mod < 2; ++mod) {
    ga.yb[mod]  = yb + mod * MODSTR;
    ga.wW[mod]  = wbf + (size_t)(mod * 4 + 3) * 131072;
    ga.wb[mod]  = in(mod, 11);
    ga.src[mod] = mod ? flow : rgb;
    ga.g[mod]   = in(mod, 0);
    ga.bb[mod]  = in(mod, 1);
    ga.mm[mod]  = in(mod, 2);
    ga.vv[mod]  = in(mod, 3);
  }
  wgemm_epi_k<<<dim3(32, 32), 256, 0, stream>>>(ga, out);
}

// Round 16
// 165.522 us; speedup vs baseline: 1.0593x; 1.0148x over previous
//
#include <hip/hip_runtime.h>

// ---------------------------------------------------------------------------
// Mutual Feature Refinement — round 16.
// Delta from round 15 (passing, 168.0 µs): proj128_k and wgemm_epi_k
// __launch_bounds__ 2nd arg 2 -> 3. Hand-counted register need ~150/wave
// fits the ~170 cap at 3 waves/SIMD; LDS (40KB) already allows 4 blocks/CU.
// Raises residency 2 -> 3 blocks/CU for the two latency-bound GEMMs.
// Everything else byte-identical to round 15.
// ---------------------------------------------------------------------------

typedef __bf16 bf16x8 __attribute__((ext_vector_type(8)));
typedef float  f32x4  __attribute__((ext_vector_type(4)));
typedef float  f32x16 __attribute__((ext_vector_type(16)));
typedef unsigned u32x4 __attribute__((ext_vector_type(4)));
static_assert(sizeof(bf16x8) == 16, "bf16x8 must be 16B");

// K tile (per 32 kv): 32 rows x 264 ushorts (256 data + 8 pad) = 8704 ushorts.
// V tile (per 32 kv): 256 c x 40 ushorts (32 data + 8 pad) = 10240 ushorts.
constexpr int KTILE = 8704;    // ushorts
constexpr int VTILE = 10240;   // ushorts
constexpr int KINST = 32 * KTILE;   // 278528
constexpr int VINST = 32 * VTILE;   // 327680

__device__ __forceinline__ ushort f2bf(float x) {
  unsigned u = __builtin_bit_cast(unsigned, x);
  u = (u + 0x7fffu + ((u >> 16) & 1u)) >> 16;   // RNE
  return (ushort)u;
}
__device__ __forceinline__ unsigned packbf(float lo, float hi) {
  return (unsigned)f2bf(lo) | ((unsigned)f2bf(hi) << 16);
}
__device__ __forceinline__ void gload_lds16(const ushort* g, ushort* l) {
  __builtin_amdgcn_global_load_lds(
      (const __attribute__((address_space(1))) void*)g,
      (__attribute__((address_space(3))) void*)l, 16, 0, 0);
}

// ---------------------------------------------------------------------------
// Weight conversion: 8 matrices of 131072 f32 -> bf16, vectorized x4.
// ---------------------------------------------------------------------------
struct WcvtArgs { const float* src[8]; };
__global__ __launch_bounds__(256) void wcvt8_k(WcvtArgs a, ushort* __restrict__ dst) {
  const int which = blockIdx.y;
  const int i = (blockIdx.x * 256 + threadIdx.x) * 4;
  float4 x = *reinterpret_cast<const float4*>(a.src[which] + i);
  ushort4 u = {f2bf(x.x), f2bf(x.y), f2bf(x.z), f2bf(x.w)};
  *reinterpret_cast<ushort4*>(dst + (size_t)which * 131072 + i) = u;
}

// ---------------------------------------------------------------------------
// Fused dual-BN transpose, vectorized (round-12, passing).
// ---------------------------------------------------------------------------
__global__ __launch_bounds__(256) void bn2_k(
    const float* __restrict__ rgb, const float* __restrict__ flow,
    const float* __restrict__ g1, const float* __restrict__ b1,
    const float* __restrict__ m1, const float* __restrict__ v1,
    const float* __restrict__ g2, const float* __restrict__ b2,
    const float* __restrict__ m2, const float* __restrict__ v2,
    ushort* __restrict__ Abn1, ushort* __restrict__ Bbn1,
    ushort* __restrict__ Abn2, ushort* __restrict__ Bbn2)
{
  const int z = blockIdx.z;
  const int b = z >> 1, which = z & 1;
  const float* src = which ? flow : rgb;
  ushort* o1 = which ? Bbn1 : Abn1;
  ushort* o2 = which ? Abn2 : Bbn2;
  src += (size_t)b * 512 * 1024;
  o1  += (size_t)b * 1024 * 512;
  o2  += (size_t)b * 1024 * 512;

  __shared__ unsigned tileU[32][36];   // [c-local][n-local], packed bn1|bn2<<16
  const int n0 = blockIdx.x * 32, c0 = blockIdx.y * 32;

  const int rc = threadIdx.x >> 3, nq = threadIdx.x & 7;
  {
    const int c = c0 + rc;
    const float s1 = g1[c] * rsqrtf(v1[c] + 1e-5f);
    const float h1 = b1[c] - m1[c] * s1;
    const float s2 = g2[c] * rsqrtf(v2[c] + 1e-5f);
    const float h2 = b2[c] - m2[c] * s2;
    float4 x = *reinterpret_cast<const float4*>(src + (size_t)c * 1024 + n0 + nq * 4);
    u32x4 u;
    u[0] = packbf(fmaxf(x.x * s1 + h1, 0.f), fmaxf(x.x * s2 + h2, 0.f));
    u[1] = packbf(fmaxf(x.y * s1 + h1, 0.f), fmaxf(x.y * s2 + h2, 0.f));
    u[2] = packbf(fmaxf(x.z * s1 + h1, 0.f), fmaxf(x.z * s2 + h2, 0.f));
    u[3] = packbf(fmaxf(x.w * s1 + h1, 0.f), fmaxf(x.w * s2 + h2, 0.f));
    *reinterpret_cast<u32x4*>(&tileU[rc][nq * 4]) = u;
  }
  __syncthreads();
  const int r = threadIdx.x >> 3, cq = threadIdx.x & 7;
  ushort4 w1, w2;
  {
    const unsigned u0 = tileU[cq * 4 + 0][r];
    const unsigned u1 = tileU[cq * 4 + 1][r];
    const unsigned u2 = tileU[cq * 4 + 2][r];
    const unsigned u3 = tileU[cq * 4 + 3][r];
    w1 = (ushort4){(ushort)(u0 & 0xffff), (ushort)(u1 & 0xffff),
                   (ushort)(u2 & 0xffff), (ushort)(u3 & 0xffff)};
    w2 = (ushort4){(ushort)(u0 >> 16), (ushort)(u1 >> 16),
                   (ushort)(u2 >> 16), (ushort)(u3 >> 16)};
  }
  const size_t base = (size_t)(n0 + r) * 512 + c0 + cq * 4;
  *reinterpret_cast<ushort4*>(o1 + base) = w1;
  *reinterpret_cast<ushort4*>(o2 + base) = w2;
}

// ---------------------------------------------------------------------------
// Unified projection GEMM, 128x128 tile, LDS-staged (reg prefetch), one
// launch for all 6. [round-13 structure; launch_bounds (256,3)]
// ---------------------------------------------------------------------------
struct ProjDesc { const ushort* W; const ushort* act; const float* bias;
                  ushort* out; int mode; };
struct ProjArgs { ProjDesc d[6]; };

__global__ __launch_bounds__(256, 3) void proj128_k(ProjArgs pa) {
  __shared__ __align__(16) ushort Al[128 * 80];
  __shared__ __align__(16) ushort Bl[128 * 80];

  const int bx = blockIdx.x;
  const int mb = bx >> 3, nb = bx & 7;
  const int by = blockIdx.y;
  const ProjDesc d = pa.d[by >> 4];
  const int inst = by & 15;
  const ushort* A = d.W;
  const ushort* Bact = d.act + (size_t)inst * 524288;

  const int tid = threadIdx.x;
  const int w = tid >> 6, lane = tid & 63;
  const int q = lane >> 4, lm = lane & 15;
  const int m0 = mb * 128, n0 = nb * 128;

  int row[4], c8[4];
  #pragma unroll
  for (int i = 0; i < 4; ++i) { int g = i * 256 + tid; row[i] = g >> 3; c8[i] = g & 7; }

  bf16x8 ast[4], bst[4];
  auto sload = [&](int kk) {
    #pragma unroll
    for (int i = 0; i < 4; ++i) {
      ast[i] = *reinterpret_cast<const bf16x8*>(A + (size_t)(m0 + row[i]) * 512 + kk + c8[i] * 8);
      bst[i] = *reinterpret_cast<const bf16x8*>(Bact + (size_t)(n0 + row[i]) * 512 + kk + c8[i] * 8);
    }
  };
  sload(0);

  f32x4 acc[4][4];
  #pragma unroll
  for (int i = 0; i < 4; ++i)
    #pragma unroll
    for (int j = 0; j < 4; ++j) acc[i][j] = (f32x4){0.f, 0.f, 0.f, 0.f};

  const int wm = (w >> 1) * 64, wn = (w & 1) * 64;

  for (int t = 0; t < 8; ++t) {
    __syncthreads();
    #pragma unroll
    for (int i = 0; i < 4; ++i) {
      *reinterpret_cast<bf16x8*>(Al + row[i] * 80 + c8[i] * 8) = ast[i];
      *reinterpret_cast<bf16x8*>(Bl + row[i] * 80 + c8[i] * 8) = bst[i];
    }
    __syncthreads();
    if (t < 7) sload((t + 1) * 64);
    #pragma unroll
    for (int ks = 0; ks < 2; ++ks) {
      bf16x8 af[4], bfr[4];
      #pragma unroll
      for (int f = 0; f < 4; ++f)
        af[f] = *reinterpret_cast<const bf16x8*>(Al + (wm + f * 16 + lm) * 80 + ks * 32 + q * 8);
      #pragma unroll
      for (int f = 0; f < 4; ++f)
        bfr[f] = *reinterpret_cast<const bf16x8*>(Bl + (wn + f * 16 + lm) * 80 + ks * 32 + q * 8);
      __builtin_amdgcn_s_setprio(1);
      #pragma unroll
      for (int fi = 0; fi < 4; ++fi)
        #pragma unroll
        for (int fj = 0; fj < 4; ++fj)
          acc[fi][fj] = __builtin_amdgcn_mfma_f32_16x16x32_bf16(af[fi], bfr[fj], acc[fi][fj], 0, 0, 0);
      __builtin_amdgcn_s_setprio(0);
    }
  }

  if (d.mode == 0) {
    ushort* out = d.out + (size_t)inst * 262144;
    #pragma unroll
    for (int fi = 0; fi < 4; ++fi)
      #pragma unroll
      for (int fj = 0; fj < 4; ++fj) {
        const int m4 = m0 + wm + fi * 16 + q * 4;
        const int n  = n0 + wn + fj * 16 + lm;
        float4 bi = *reinterpret_cast<const float4*>(d.bias + m4);
        ushort4 u = {f2bf(acc[fi][fj][0] + bi.x), f2bf(acc[fi][fj][1] + bi.y),
                     f2bf(acc[fi][fj][2] + bi.z), f2bf(acc[fi][fj][3] + bi.w)};
        *reinterpret_cast<ushort4*>(out + (size_t)n * 256 + m4) = u;
      }
  } else if (d.mode == 1) {
    // Kg: ushort index = (n>>5)*KTILE + (n&31)*264 + m
    ushort* out = d.out + (size_t)inst * KINST;
    #pragma unroll
    for (int fi = 0; fi < 4; ++fi)
      #pragma unroll
      for (int fj = 0; fj < 4; ++fj) {
        const int m4 = m0 + wm + fi * 16 + q * 4;
        const int n  = n0 + wn + fj * 16 + lm;
        float4 bi = *reinterpret_cast<const float4*>(d.bias + m4);
        ushort4 u = {f2bf(acc[fi][fj][0] + bi.x), f2bf(acc[fi][fj][1] + bi.y),
                     f2bf(acc[fi][fj][2] + bi.z), f2bf(acc[fi][fj][3] + bi.w)};
        *reinterpret_cast<ushort4*>(out + (size_t)(n >> 5) * KTILE + (n & 31) * 264 + m4) = u;
      }
  } else {
    // Vg: ushort index = (n>>5)*VTILE + m*40 + ((n&31)>>3)*8 + (n&7)
    ushort* out = d.out + (size_t)inst * VINST;
    #pragma unroll
    for (int fi = 0; fi < 4; ++fi)
      #pragma unroll
      for (int fj = 0; fj < 4; ++fj) {
        const int n = n0 + wn + fj * 16 + lm;
        const size_t base = (size_t)(n >> 5) * VTILE + ((n & 31) >> 3) * 8 + (n & 7);
        #pragma unroll
        for (int j = 0; j < 4; ++j) {
          const int m = m0 + wm + fi * 16 + q * 4 + j;
          out[base + (size_t)m * 40] = f2bf(acc[fi][fj][j] + d.bias[m]);
        }
      }
  }
}

// ---------------------------------------------------------------------------
// Flash attention — round-6 kernel (single S chain, setprio). [byte-identical]
// ---------------------------------------------------------------------------
__global__ __launch_bounds__(256, 2) void flash_k(
    const ushort* __restrict__ Qp, const ushort* __restrict__ Kg,
    const ushort* __restrict__ Vg, ushort* __restrict__ Op)
{
  __shared__ __align__(16) ushort KV[2][KTILE + VTILE];  // 2 x 37888B
  __shared__ float2 stat2[2][32];

  const int raw = blockIdx.x;
  const int xcd = raw & 7, loc = raw >> 3;
  const int inst = xcd * 4 + (loc >> 4);   // each XCD owns 4 instances
  const int qb = loc & 15;

  const int tid = threadIdx.x;
  const int w = tid >> 6, lane = tid & 63;
  const int u = w & 1, p = w >> 1;
  const int h = lane >> 5, lm5 = lane & 31;

  const ushort* Q  = Qp + (size_t)inst * 262144;
  const ushort* Kt = Kg + (size_t)inst * KINST + (size_t)p * 16 * KTILE;
  const ushort* Vt = Vg + (size_t)inst * VINST + (size_t)p * 16 * VTILE;

  ushort* Klds = &KV[p][0];
  ushort* Vlds = &KV[p][KTILE];

  const int nrow0 = qb * 64 + u * 32;

  bf16x8 qf[16];
  #pragma unroll
  for (int cs = 0; cs < 16; ++cs)
    qf[cs] = *reinterpret_cast<const bf16x8*>(
        Q + (size_t)(nrow0 + lm5) * 256 + cs * 16 + h * 8);

  f32x16 acc[8];
  #pragma unroll
  for (int cb = 0; cb < 8; ++cb)
    #pragma unroll
    for (int i = 0; i < 16; ++i) acc[cb][i] = 0.f;

  float run_m = -__builtin_inff();
  float run_l = 0.f;

  auto stageK = [&](int t) {
    const ushort* src = Kt + (size_t)t * KTILE;
    const int base = u ? 9 : 0;
    #pragma unroll
    for (int j = 0; j < 9; ++j)
      if (u == 0 || j < 8)
        gload_lds16(src + (base + j) * 512 + lane * 8, Klds + (base + j) * 512);
  };
  auto stageV = [&](int t) {
    const ushort* src = Vt + (size_t)t * VTILE;
    #pragma unroll
    for (int j = 0; j < 10; ++j)
      gload_lds16(src + (u * 10 + j) * 512 + lane * 8, Vlds + (u * 10 + j) * 512);
  };

  stageK(0);
  stageV(0);
  asm volatile("s_waitcnt vmcnt(0)" ::: "memory");
  __builtin_amdgcn_sched_barrier(0);
  __builtin_amdgcn_s_barrier();

  for (int t = 0; t < 16; ++t) {
    // ---- QK^T: S[kv=(r&3)+8*(r>>2)+4h][q=lm5]
    f32x16 S;
    #pragma unroll
    for (int i = 0; i < 16; ++i) S[i] = 0.f;
    __builtin_amdgcn_s_setprio(1);
    #pragma unroll
    for (int cs = 0; cs < 16; ++cs) {
      bf16x8 kf = *reinterpret_cast<const bf16x8*>(
          Klds + lm5 * 264 + (cs * 2 + h) * 8);
      S = __builtin_amdgcn_mfma_f32_32x32x16_bf16(kf, qf[cs], S, 0, 0, 0);
    }
    __builtin_amdgcn_s_setprio(0);

    // V(t) has landed (issued last iter; covered by QK); barrier A.
    __builtin_amdgcn_sched_barrier(0);
    asm volatile("s_waitcnt vmcnt(0)" ::: "memory");
    __builtin_amdgcn_sched_barrier(0);
    __builtin_amdgcn_s_barrier();          // A: Klds(t) free, Vlds(t) visible
    __builtin_amdgcn_sched_barrier(0);
    if (t < 15) stageK(t + 1);             // K(t+1) hides under softmax+PV

    // ---- online softmax (per-lane stats; cross-half via shfl_xor 32)
    float ml = fmaxf(fmaxf(fmaxf(S[0], S[1]), fmaxf(S[2], S[3])),
                     fmaxf(fmaxf(S[4], S[5]), fmaxf(S[6], S[7])));
    ml = fmaxf(ml, fmaxf(fmaxf(fmaxf(S[8], S[9]), fmaxf(S[10], S[11])),
                         fmaxf(fmaxf(S[12], S[13]), fmaxf(S[14], S[15]))));
    ml = fmaxf(ml, __shfl_xor(ml, 32));
    const float mnew = fmaxf(run_m, ml);
    if (!__all(ml <= run_m + 8.f)) {      // defer-max
      const float sc = __expf(run_m - mnew);
      run_m = mnew;
      run_l *= sc;
      #pragma unroll
      for (int cb = 0; cb < 8; ++cb) acc[cb] *= sc;
    }
    #pragma unroll
    for (int i = 0; i < 16; ++i) S[i] = __expf(S[i] - run_m);
    float ts = ((S[0] + S[1]) + (S[2] + S[3])) + ((S[4] + S[5]) + (S[6] + S[7]));
    ts += ((S[8] + S[9]) + (S[10] + S[11])) + ((S[12] + S[13]) + (S[14] + S[15]));
    ts += __shfl_xor(ts, 32);
    run_l += ts;

    // ---- pack P to bf16 pairs; partner values via shfl_xor 32
    const unsigned pk0 = packbf(S[0], S[1]),   pk1 = packbf(S[2], S[3]);
    const unsigned pk2 = packbf(S[4], S[5]),   pk3 = packbf(S[6], S[7]);
    const unsigned pk4 = packbf(S[8], S[9]),   pk5 = packbf(S[10], S[11]);
    const unsigned pk6 = packbf(S[12], S[13]), pk7 = packbf(S[14], S[15]);
    const unsigned sx0 = __shfl_xor(pk0, 32), sx1 = __shfl_xor(pk1, 32);
    const unsigned sx2 = __shfl_xor(pk2, 32), sx3 = __shfl_xor(pk3, 32);
    const unsigned sx4 = __shfl_xor(pk4, 32), sx5 = __shfl_xor(pk5, 32);
    const unsigned sx6 = __shfl_xor(pk6, 32), sx7 = __shfl_xor(pk7, 32);
    const bool hh = (h != 0);
    u32x4 B0, B1;
    B0[0] = hh ? sx2 : pk0;  B0[1] = hh ? sx3 : pk1;
    B0[2] = hh ? pk2 : sx0;  B0[3] = hh ? pk3 : sx1;
    B1[0] = hh ? sx6 : pk4;  B1[1] = hh ? sx7 : pk5;
    B1[2] = hh ? pk6 : sx4;  B1[3] = hh ? pk7 : sx5;
    const bf16x8 pf0 = __builtin_bit_cast(bf16x8, B0);
    const bf16x8 pf1 = __builtin_bit_cast(bf16x8, B1);

    // ---- PV: acc[cb] += V^T(c rows) x P   (v0: kv 0-15, v1: kv 16-31)
    __builtin_amdgcn_s_setprio(1);
    #pragma unroll
    for (int cb = 0; cb < 8; ++cb) {
      bf16x8 v0 = *reinterpret_cast<const bf16x8*>(
          Vlds + (cb * 32 + lm5) * 40 + h * 8);
      bf16x8 v1 = *reinterpret_cast<const bf16x8*>(
          Vlds + (cb * 32 + lm5) * 40 + (2 + h) * 8);
      acc[cb] = __builtin_amdgcn_mfma_f32_32x32x16_bf16(v0, pf0, acc[cb], 0, 0, 0);
      acc[cb] = __builtin_amdgcn_mfma_f32_32x32x16_bf16(v1, pf1, acc[cb], 0, 0, 0);
    }
    __builtin_amdgcn_s_setprio(0);

    __builtin_amdgcn_sched_barrier(0);
    __builtin_amdgcn_s_barrier();          // B: Vlds(t) free
    __builtin_amdgcn_sched_barrier(0);
    if (t < 15) {
      stageV(t + 1);                       // V(t+1) hides under next QK
      asm volatile("s_waitcnt vmcnt(10)" ::: "memory");  // K(t+1) done, V in flight
    } else {
      asm volatile("s_waitcnt vmcnt(0)" ::: "memory");
    }
    __builtin_amdgcn_sched_barrier(0);
    __builtin_amdgcn_s_barrier();          // C: Klds(t+1) visible
    __builtin_amdgcn_sched_barrier(0);
  }

  // ---- pair merge (p=1 -> LDS -> p=0 combines) and bf16 store
  __syncthreads();
  if (p == 1 && lane < 32) stat2[u][lm5] = make_float2(run_m, run_l);

  float a0 = 1.f, a1 = 0.f, inv = 1.f;
  float4* mb = reinterpret_cast<float4*>(&KV[0][0]);
  #pragma unroll
  for (int half = 0; half < 2; ++half) {
    __syncthreads();
    if (p == 1) {
      #pragma unroll
      for (int cb2 = 0; cb2 < 4; ++cb2) {
        const int cb = half * 4 + cb2;
        #pragma unroll
        for (int r4 = 0; r4 < 4; ++r4) {
          float4 v = {acc[cb][r4 * 4 + 0], acc[cb][r4 * 4 + 1],
                      acc[cb][r4 * 4 + 2], acc[cb][r4 * 4 + 3]};
          mb[u * 1024 + cb2 * 256 + r4 * 64 + lane] = v;
        }
      }
    }
    __syncthreads();
    if (p == 0) {
      if (half == 0) {
        const float2 s1 = stat2[u][lm5];
        const float M = fmaxf(run_m, s1.x);
        a0 = __expf(run_m - M);
        a1 = __expf(s1.x - M);
        inv = 1.f / (a0 * run_l + a1 * s1.y);
      }
      ushort* Ob = Op + (size_t)inst * 262144 + (size_t)(nrow0 + lm5) * 256;
      #pragma unroll
      for (int cb2 = 0; cb2 < 4; ++cb2) {
        const int cb = half * 4 + cb2;
        #pragma unroll
        for (int r4 = 0; r4 < 4; ++r4) {
          float4 o = mb[u * 1024 + cb2 * 256 + r4 * 64 + lane];
          ushort4 s;
          s.x = f2bf((a0 * acc[cb][r4 * 4 + 0] + a1 * o.x) * inv);
          s.y = f2bf((a0 * acc[cb][r4 * 4 + 1] + a1 * o.y) * inv);
          s.z = f2bf((a0 * acc[cb][r4 * 4 + 2] + a1 * o.z) * inv);
          s.w = f2bf((a0 * acc[cb][r4 * 4 + 3] + a1 * o.w) * inv);
          *reinterpret_cast<ushort4*>(Ob + cb * 32 + r4 * 8 + h * 4) = s;
        }
      }
    }
  }
}

// ---------------------------------------------------------------------------
// W-projection GEMM with fused BN-residual epilogue — proj128 structure.
// [round-13 structure; launch_bounds (256,3)]
// ---------------------------------------------------------------------------
struct WgemmArgs {
  const ushort* yb[2]; const ushort* wW[2]; const float* wb[2];
  const float* src[2]; const float* g[2]; const float* bb[2];
  const float* mm[2]; const float* vv[2];
};

__global__ __launch_bounds__(256, 3) void wgemm_epi_k(WgemmArgs a, float* __restrict__ outp) {
  __shared__ __align__(16) ushort Al[128 * 80];
  __shared__ __align__(16) ushort Bl[128 * 80];

  const int bx = blockIdx.x;
  const int mb = bx >> 2, nb = bx & 3;      // 8 n-blocks x 4 c-blocks
  const int by = blockIdx.y;
  const int mod = by >> 4, b = by & 15;

  const ushort* A  = a.yb[mod] + (size_t)b * 262144;   // rows n, K=256
  const ushort* Bw = a.wW[mod];                         // rows c, K=256
  const float* wb  = a.wb[mod];
  const float* src = a.src[mod] + (size_t)b * 512 * 1024;
  const float* g   = a.g[mod];
  const float* bbp = a.bb[mod];
  const float* mm  = a.mm[mod];
  const float* vv  = a.vv[mod];
  float* out = outp + (size_t)mod * 16 * 512 * 1024 + (size_t)b * 512 * 1024;

  const int tid = threadIdx.x;
  const int w = tid >> 6, lane = tid & 63;
  const int q = lane >> 4, lm = lane & 15;
  const int m0 = mb * 128, n0 = nb * 128;   // m0: n-dim base, n0: c-dim base

  int row[4], c8[4];
  #pragma unroll
  for (int i = 0; i < 4; ++i) { int gg = i * 256 + tid; row[i] = gg >> 3; c8[i] = gg & 7; }

  bf16x8 ast[4], bst[4];
  auto sload = [&](int kk) {
    #pragma unroll
    for (int i = 0; i < 4; ++i) {
      ast[i] = *reinterpret_cast<const bf16x8*>(A  + (size_t)(m0 + row[i]) * 256 + kk + c8[i] * 8);
      bst[i] = *reinterpret_cast<const bf16x8*>(Bw + (size_t)(n0 + row[i]) * 256 + kk + c8[i] * 8);
    }
  };
  sload(0);

  f32x4 acc[4][4];
  #pragma unroll
  for (int i = 0; i < 4; ++i)
    #pragma unroll
    for (int j = 0; j < 4; ++j) acc[i][j] = (f32x4){0.f, 0.f, 0.f, 0.f};

  const int wm = (w >> 1) * 64, wn = (w & 1) * 64;

  for (int t = 0; t < 4; ++t) {
    __syncthreads();
    #pragma unroll
    for (int i = 0; i < 4; ++i) {
      *reinterpret_cast<bf16x8*>(Al + row[i] * 80 + c8[i] * 8) = ast[i];
      *reinterpret_cast<bf16x8*>(Bl + row[i] * 80 + c8[i] * 8) = bst[i];
    }
    __syncthreads();
    if (t < 3) sload((t + 1) * 64);
    #pragma unroll
    for (int ks = 0; ks < 2; ++ks) {
      bf16x8 af[4], bfr[4];
      #pragma unroll
      for (int f = 0; f < 4; ++f)
        af[f] = *reinterpret_cast<const bf16x8*>(Al + (wm + f * 16 + lm) * 80 + ks * 32 + q * 8);
      #pragma unroll
      for (int f = 0; f < 4; ++f)
        bfr[f] = *reinterpret_cast<const bf16x8*>(Bl + (wn + f * 16 + lm) * 80 + ks * 32 + q * 8);
      __builtin_amdgcn_s_setprio(1);
      #pragma unroll
      for (int fi = 0; fi < 4; ++fi)
        #pragma unroll
        for (int fj = 0; fj < 4; ++fj)
          acc[fi][fj] = __builtin_amdgcn_mfma_f32_16x16x32_bf16(af[fi], bfr[fj], acc[fi][fj], 0, 0, 0);
      __builtin_amdgcn_s_setprio(0);
    }
  }

  #pragma unroll
  for (int fj = 0; fj < 4; ++fj) {
    const int c = n0 + wn + fj * 16 + lm;
    const float sc = g[c] * rsqrtf(vv[c] + 1e-5f);
    const float sh = bbp[c] - mm[c] * sc;
    const float bv = wb[c];
    #pragma unroll
    for (int fi = 0; fi < 4; ++fi) {
      const int n4 = m0 + wm + fi * 16 + q * 4;
      const size_t base = (size_t)c * 1024 + n4;
      float4 x = *reinterpret_cast<const float4*>(src + base);
      float4 v;
      v.x = acc[fi][fj][0] + bv + fmaxf(x.x * sc + sh, 0.f);
      v.y = acc[fi][fj][1] + bv + fmaxf(x.y * sc + sh, 0.f);
      v.z = acc[fi][fj][2] + bv + fmaxf(x.z * sc + sh, 0.f);
      v.w = acc[fi][fj][3] + bv + fmaxf(x.w * sc + sh, 0.f);
      *reinterpret_cast<float4*>(out + base) = v;
    }
  }
}

// ---------------------------------------------------------------------------
// Workspace layout (bytes), ~136 MB.
// ---------------------------------------------------------------------------
constexpr size_t MB = 1ull << 20;
constexpr size_t OFF_WBF = 0;          // 2 MB: [2][4][131072] bf16
constexpr size_t OFF_BN  = 2 * MB;     // 64 MB: Abn1/Bbn1/Abn2/Bbn2
constexpr size_t OFF_TH  = 66 * MB;    // 16 MB [32 inst][1024][256]
constexpr size_t OFF_KG  = 82 * MB;    // 17 MB [32 inst][KINST]
constexpr size_t OFF_VG  = 100 * MB;   // 20 MB [32 inst][VINST]
constexpr size_t OFF_YB  = 120 * MB;   // 16 MB [32 inst][1024][256]

extern "C" void kernel_launch(void* const* d_in, const int* in_sizes, int n_in,
                              void* d_out, int out_size, void* d_ws, size_t ws_size,
                              hipStream_t stream) {
  const float* rgb  = (const float*)d_in[0];
  const float* flow = (const float*)d_in[1];
  auto in = [&](int mod, int j) { return (const float*)d_in[2 + mod * 12 + j]; };
  // j: 0 bn_g, 1 bn_b, 2 bn_m, 3 bn_v, 4 th_w, 5 th_b, 6 ph_w, 7 ph_b,
  //    8 g_w, 9 g_b, 10 w_w, 11 w_b

  char* ws = (char*)d_ws;
  ushort* wbf  = (ushort*)(ws + OFF_WBF);
  ushort* Abn1 = (ushort*)(ws + OFF_BN);
  ushort* Bbn1 = (ushort*)(ws + OFF_BN + 16 * MB);
  ushort* Abn2 = (ushort*)(ws + OFF_BN + 32 * MB);
  ushort* Bbn2 = (ushort*)(ws + OFF_BN + 48 * MB);
  ushort* th   = (ushort*)(ws + OFF_TH);
  ushort* Kgx  = (ushort*)(ws + OFF_KG);
  ushort* Vgx  = (ushort*)(ws + OFF_VG);
  ushort* yb   = (ushort*)(ws + OFF_YB);
  float*  out  = (float*)d_out;

  const size_t MODSTR = (size_t)16 * 262144;

  // 1) weights -> bf16 (vectorized x4)
  WcvtArgs wa;
  for (int mod = 0; mod < 2; ++mod) {
    wa.src[mod * 4 + 0] = in(mod, 4);
    wa.src[mod * 4 + 1] = in(mod, 6);
    wa.src[mod * 4 + 2] = in(mod, 8);
    wa.src[mod * 4 + 3] = in(mod, 10);
  }
  wcvt8_k<<<dim3(128, 8), 256, 0, stream>>>(wa, wbf);

  // 2) fused dual-BN transpose (vectorized)
  bn2_k<<<dim3(32, 16, 32), 256, 0, stream>>>(
      rgb, flow,
      in(0, 0), in(0, 1), in(0, 2), in(0, 3),
      in(1, 0), in(1, 1), in(1, 2), in(1, 3),
      Abn1, Bbn1, Abn2, Bbn2);

  // 3) all six projections, one launch
  ProjArgs pa;
  for (int mod = 0; mod < 2; ++mod) {
    const ushort* wb4 = wbf + (size_t)mod * 4 * 131072;
    ushort* Abn = mod ? Abn2 : Abn1;
    ushort* Bbn = mod ? Bbn2 : Bbn1;
    pa.d[mod * 3 + 0] = {wb4,              Abn, in(mod, 5), th + mod * MODSTR,               0};
    pa.d[mod * 3 + 1] = {wb4 + 131072,     Bbn, in(mod, 7), Kgx + (size_t)mod * 16 * KINST, 1};
    pa.d[mod * 3 + 2] = {wb4 + 2 * 131072, Abn, in(mod, 9), Vgx + (size_t)mod * 16 * VINST, 2};
  }
  proj128_k<<<dim3(16, 96), 256, 0, stream>>>(pa);

  // 4) flash attention (both modules, in-block KV-split, XCD-chunked)
  flash_k<<<dim3(512), 256, 0, stream>>>(th, Kgx, Vgx, yb);

  // 5) W-projection + BN-residual epilogue, both modules in one launch
  WgemmArgs ga;
  for (int mod = 0; mod < 2; ++mod) {
    ga.yb[mod]  = yb + mod * MODSTR;
    ga.wW[mod]  = wbf + (size_t)(mod * 4 + 3) * 131072;
    ga.wb[mod]  = in(mod, 11);
    ga.src[mod] = mod ? flow : rgb;
    ga.g[mod]   = in(mod, 0);
    ga.bb[mod]  = in(mod, 1);
    ga.mm[mod]  = in(mod, 2);
    ga.vv[mod]  = in(mod, 3);
  }
  wgemm_epi_k<<<dim3(32, 32), 256, 0, stream>>>(ga, out);
}